// Round 1
// baseline (63.352 us; speedup 1.0000x reference)
//
#include <hip/hip_runtime.h>
#include <utility>

// ============================================================================
// Compile-time Clebsch-Gordan coefficients (port of the e3nn-convention math
// from the reference). All evaluated by the compiler; zeros fold away.
// ============================================================================
namespace cgc {

constexpr double cfact(int n) {
    double r = 1.0;
    for (int i = 2; i <= n; ++i) r *= (double)i;
    return r;
}

constexpr double csqrt(double x) {
    if (x <= 0.0) return 0.0;
    double g = x > 1.0 ? x : 1.0;
    for (int it = 0; it < 64; ++it) {
        double ng = 0.5 * (g + x / g);
        if (ng == g) break;
        g = ng;
    }
    return g;
}

struct cplx { double re; double im; };
constexpr cplx cadd(cplx a, cplx b) { return {a.re + b.re, a.im + b.im}; }
constexpr cplx cmul(cplx a, cplx b) {
    return {a.re * b.re - a.im * b.im, a.re * b.im + a.im * b.re};
}
constexpr cplx cconj(cplx a) { return {a.re, -a.im}; }

constexpr double su2_cg_coef(int j1, int m1, int j2, int m2, int j3, int m3) {
    double pref = csqrt((2.0 * j3 + 1.0) * cfact(j3 + j1 - j2) * cfact(j3 - j1 + j2) *
                        cfact(j1 + j2 - j3) / cfact(j1 + j2 + j3 + 1));
    pref *= csqrt(cfact(j3 + m3) * cfact(j3 - m3) * cfact(j1 - m1) * cfact(j1 + m1) *
                  cfact(j2 - m2) * cfact(j2 + m2));
    double s = 0.0;
    for (int k = 0; k <= j1 + j2 - j3; ++k) {
        int d0 = k, d1 = j1 + j2 - j3 - k, d2 = j1 - m1 - k;
        int d3 = j2 + m2 - k, d4 = j3 - j2 + m1 + k, d5 = j3 - j1 - m2 + k;
        if (d0 < 0 || d1 < 0 || d2 < 0 || d3 < 0 || d4 < 0 || d5 < 0) continue;
        double denom = cfact(d0) * cfact(d1) * cfact(d2) * cfact(d3) * cfact(d4) * cfact(d5);
        s += ((k & 1) ? -1.0 : 1.0) / denom;
    }
    return pref * s;
}

struct T3  { double v[5][5][5]; };
struct M2  { cplx v[5][5]; };
struct CT3 { cplx v[5][5][5]; };

constexpr T3 su2_cg(int j1, int j2, int j3) {
    T3 C{};
    for (int m1 = -j1; m1 <= j1; ++m1)
        for (int m2 = -j2; m2 <= j2; ++m2) {
            int m3 = m1 + m2;
            if (m3 >= -j3 && m3 <= j3)
                C.v[j1 + m1][j2 + m2][j3 + m3] = su2_cg_coef(j1, m1, j2, m2, j3, m3);
        }
    return C;
}

constexpr M2 real_to_complex(int l) {
    M2 q{};
    const double s = csqrt(0.5);
    for (int m = -l; m < 0; ++m) {
        q.v[l + m][l - m] = cplx{s, 0.0};    // col l+abs(m)
        q.v[l + m][l + m] = cplx{0.0, -s};   // col l-abs(m)
    }
    q.v[l][l] = cplx{1.0, 0.0};
    for (int m = 1; m <= l; ++m) {
        double sg = (m & 1) ? -1.0 : 1.0;
        q.v[l + m][l + m] = cplx{sg * s, 0.0};
        q.v[l + m][l - m] = cplx{0.0, sg * s};
    }
    cplx ph{1.0, 0.0};
    for (int i = 0; i < l; ++i) ph = cmul(ph, cplx{0.0, -1.0});  // (-1j)^l
    for (int r = 0; r < 2 * l + 1; ++r)
        for (int c = 0; c < 2 * l + 1; ++c)
            q.v[r][c] = cmul(q.v[r][c], ph);
    return q;
}

// einsum('ij,kl,mn,ikn->jlm', Q1, Q2, conj(Q3.T), Csu2), staged to keep
// constexpr step count low; then real part, Frobenius-normalized.
constexpr T3 so3_cg(int l1, int l2, int l3) {
    M2 Q1 = real_to_complex(l1);
    M2 Q2 = real_to_complex(l2);
    M2 Q3 = real_to_complex(l3);
    T3 Cs = su2_cg(l1, l2, l3);
    int n1 = 2 * l1 + 1, n2 = 2 * l2 + 1, n3 = 2 * l3 + 1;
    CT3 t1{};
    for (int j = 0; j < n1; ++j)
        for (int k = 0; k < n2; ++k)
            for (int n = 0; n < n3; ++n) {
                cplx acc{0.0, 0.0};
                for (int i = 0; i < n1; ++i)
                    acc = cadd(acc, cmul(Q1.v[i][j], cplx{Cs.v[i][k][n], 0.0}));
                t1.v[j][k][n] = acc;
            }
    CT3 t2{};
    for (int j = 0; j < n1; ++j)
        for (int L = 0; L < n2; ++L)
            for (int n = 0; n < n3; ++n) {
                cplx acc{0.0, 0.0};
                for (int k = 0; k < n2; ++k)
                    acc = cadd(acc, cmul(Q2.v[k][L], t1.v[j][k][n]));
                t2.v[j][L][n] = acc;
            }
    T3 R{};
    double norm2 = 0.0;
    for (int j = 0; j < n1; ++j)
        for (int L = 0; L < n2; ++L)
            for (int m = 0; m < n3; ++m) {
                cplx acc{0.0, 0.0};
                for (int n = 0; n < n3; ++n)
                    acc = cadd(acc, cmul(cconj(Q3.v[n][m]), t2.v[j][L][n]));
                R.v[j][L][m] = acc.re;
                norm2 += acc.re * acc.re;
            }
    double nrm = csqrt(norm2);
    if (nrm > 0.0)
        for (int j = 0; j < n1; ++j)
            for (int L = 0; L < n2; ++L)
                for (int m = 0; m < n3; ++m)
                    R.v[j][L][m] /= nrm;
    return R;
}

template <int LA, int LH, int LO>
constexpr T3 CGT = so3_cg(LA, LH, LO);

}  // namespace cgc

// ============================================================================
// Device side
// ============================================================================
template <typename F, int... Is>
__device__ __forceinline__ void unroll_impl(F&& f, std::integer_sequence<int, Is...>) {
    (f(std::integral_constant<int, Is>{}), ...);
}
template <int N, typename F>
__device__ __forceinline__ void unroll(F&& f) {
    unroll_impl(static_cast<F&&>(f), std::make_integer_sequence<int, N>{});
}

// o[k] += w * sum_{i,j} C[i][j][k] * a[i] * h[j], zeros folded at compile time.
template <int LA, int LH, int LO>
__device__ __forceinline__ void combo(float w, const float* a, const float* h, float* o) {
    constexpr int DA = 2 * LA + 1, DH = 2 * LH + 1, DO = 2 * LO + 1;
    unroll<DO>([&](auto kc) {
        constexpr int k = decltype(kc)::value;
        float s = 0.f;
        unroll<DA * DH>([&](auto tc) {
            constexpr int t = decltype(tc)::value;
            constexpr int i = t / DH;
            constexpr int j = t % DH;
            constexpr double cd = cgc::CGT<LA, LH, LO>.v[i][j][k];
            if constexpr (cd > 1e-12 || cd < -1e-12) {
                constexpr float c = (float)cd;
                s = fmaf(c, a[i] * h[j], s);
            }
        });
        o[k] = fmaf(w, s, o[k]);
    });
}

__device__ __forceinline__ void compute_edge(const float* a, const float* h,
                                             const float* W0, const float* W1,
                                             const float* W2, float* o) {
#pragma unroll
    for (int k = 0; k < 9; ++k) o[k] = 0.f;
    // combo order == Python _valid_combos order (ai outer, hi inner)
    combo<0, 0, 0>(W0[0], a + 0, h + 0, o + 0);
    combo<1, 1, 0>(W0[1], a + 1, h + 1, o + 0);
    combo<2, 2, 0>(W0[2], a + 4, h + 4, o + 0);
    combo<0, 1, 1>(W1[0], a + 0, h + 1, o + 1);
    combo<1, 0, 1>(W1[1], a + 1, h + 0, o + 1);
    combo<1, 1, 1>(W1[2], a + 1, h + 1, o + 1);
    combo<1, 2, 1>(W1[3], a + 1, h + 4, o + 1);
    combo<2, 1, 1>(W1[4], a + 4, h + 1, o + 1);
    combo<2, 2, 1>(W1[5], a + 4, h + 4, o + 1);
    combo<0, 2, 2>(W2[0], a + 0, h + 4, o + 4);
    combo<1, 1, 2>(W2[1], a + 1, h + 1, o + 4);
    combo<1, 2, 2>(W2[2], a + 1, h + 4, o + 4);
    combo<2, 0, 2>(W2[3], a + 4, h + 0, o + 4);
    combo<2, 1, 2>(W2[4], a + 4, h + 1, o + 4);
    combo<2, 2, 2>(W2[5], a + 4, h + 4, o + 4);
}

// 4 edges per thread: every global access is an aligned float4.
__global__ __launch_bounds__(256) void gnn_quad(
    const float* __restrict__ a0, const float* __restrict__ a1, const float* __restrict__ a2,
    const float* __restrict__ h0, const float* __restrict__ h1, const float* __restrict__ h2,
    const float* __restrict__ w0, const float* __restrict__ w1, const float* __restrict__ w2,
    float* __restrict__ out, int nq) {
    int q = blockIdx.x * blockDim.x + threadIdx.x;
    if (q >= nq) return;

    float W0[3], W1[6], W2[6];
#pragma unroll
    for (int i = 0; i < 3; ++i) W0[i] = w0[i];
#pragma unroll
    for (int i = 0; i < 6; ++i) W1[i] = w1[i];
#pragma unroll
    for (int i = 0; i < 6; ++i) W2[i] = w2[i];

    const float4* a0q = (const float4*)a0;
    const float4* a1q = (const float4*)a1;
    const float4* a2q = (const float4*)a2;
    const float4* h0q = (const float4*)h0;
    const float4* h1q = (const float4*)h1;
    const float4* h2q = (const float4*)h2;

    size_t qs = (size_t)q;
    float4 A0 = a0q[qs];
    float4 A1a = a1q[3 * qs + 0], A1b = a1q[3 * qs + 1], A1c = a1q[3 * qs + 2];
    float4 A2v[5];
#pragma unroll
    for (int i = 0; i < 5; ++i) A2v[i] = a2q[5 * qs + i];
    float4 H0 = h0q[qs];
    float4 H1a = h1q[3 * qs + 0], H1b = h1q[3 * qs + 1], H1c = h1q[3 * qs + 2];
    float4 H2v[5];
#pragma unroll
    for (int i = 0; i < 5; ++i) H2v[i] = h2q[5 * qs + i];

    float a0f[4] = {A0.x, A0.y, A0.z, A0.w};
    float a1f[12] = {A1a.x, A1a.y, A1a.z, A1a.w, A1b.x, A1b.y,
                     A1b.z, A1b.w, A1c.x, A1c.y, A1c.z, A1c.w};
    float a2f[20];
#pragma unroll
    for (int i = 0; i < 5; ++i) {
        a2f[4 * i + 0] = A2v[i].x; a2f[4 * i + 1] = A2v[i].y;
        a2f[4 * i + 2] = A2v[i].z; a2f[4 * i + 3] = A2v[i].w;
    }
    float h0f[4] = {H0.x, H0.y, H0.z, H0.w};
    float h1f[12] = {H1a.x, H1a.y, H1a.z, H1a.w, H1b.x, H1b.y,
                     H1b.z, H1b.w, H1c.x, H1c.y, H1c.z, H1c.w};
    float h2f[20];
#pragma unroll
    for (int i = 0; i < 5; ++i) {
        h2f[4 * i + 0] = H2v[i].x; h2f[4 * i + 1] = H2v[i].y;
        h2f[4 * i + 2] = H2v[i].z; h2f[4 * i + 3] = H2v[i].w;
    }

    float of[36];
#pragma unroll
    for (int r = 0; r < 4; ++r) {
        float a[9], h[9], o[9];
        a[0] = a0f[r];
#pragma unroll
        for (int c = 0; c < 3; ++c) a[1 + c] = a1f[r * 3 + c];
#pragma unroll
        for (int c = 0; c < 5; ++c) a[4 + c] = a2f[r * 5 + c];
        h[0] = h0f[r];
#pragma unroll
        for (int c = 0; c < 3; ++c) h[1 + c] = h1f[r * 3 + c];
#pragma unroll
        for (int c = 0; c < 5; ++c) h[4 + c] = h2f[r * 5 + c];
        compute_edge(a, h, W0, W1, W2, o);
#pragma unroll
        for (int k = 0; k < 9; ++k) of[r * 9 + k] = o[k];
    }

    float4* oq = (float4*)(out + qs * 36);
#pragma unroll
    for (int i = 0; i < 9; ++i)
        oq[i] = make_float4(of[4 * i + 0], of[4 * i + 1], of[4 * i + 2], of[4 * i + 3]);
}

// scalar tail for E % 4 != 0 (not hit for E = 2,000,000, kept for safety)
__global__ void gnn_tail(
    const float* __restrict__ a0, const float* __restrict__ a1, const float* __restrict__ a2,
    const float* __restrict__ h0, const float* __restrict__ h1, const float* __restrict__ h2,
    const float* __restrict__ w0, const float* __restrict__ w1, const float* __restrict__ w2,
    float* __restrict__ out, int E_, int start) {
    int e = start + blockIdx.x * blockDim.x + threadIdx.x;
    if (e >= E_) return;
    float W0[3], W1[6], W2[6];
#pragma unroll
    for (int i = 0; i < 3; ++i) W0[i] = w0[i];
#pragma unroll
    for (int i = 0; i < 6; ++i) W1[i] = w1[i];
#pragma unroll
    for (int i = 0; i < 6; ++i) W2[i] = w2[i];
    float a[9], h[9], o[9];
    size_t es = (size_t)e;
    a[0] = a0[es];
#pragma unroll
    for (int c = 0; c < 3; ++c) a[1 + c] = a1[3 * es + c];
#pragma unroll
    for (int c = 0; c < 5; ++c) a[4 + c] = a2[5 * es + c];
    h[0] = h0[es];
#pragma unroll
    for (int c = 0; c < 3; ++c) h[1 + c] = h1[3 * es + c];
#pragma unroll
    for (int c = 0; c < 5; ++c) h[4 + c] = h2[5 * es + c];
    compute_edge(a, h, W0, W1, W2, o);
#pragma unroll
    for (int k = 0; k < 9; ++k) out[es * 9 + k] = o[k];
}

extern "C" void kernel_launch(void* const* d_in, const int* in_sizes, int n_in,
                              void* d_out, int out_size, void* d_ws, size_t ws_size,
                              hipStream_t stream) {
    (void)n_in; (void)d_ws; (void)ws_size; (void)out_size;
    const float *a0, *a1, *a2, *h0, *h1, *h2;
    // setup_inputs() dict order interleaves: a0,h0,a1,h1,a2,h2. Detect by sizes
    // in case the harness used the reference-signature order instead.
    if (in_sizes[1] == in_sizes[0]) {
        a0 = (const float*)d_in[0]; h0 = (const float*)d_in[1];
        a1 = (const float*)d_in[2]; h1 = (const float*)d_in[3];
        a2 = (const float*)d_in[4]; h2 = (const float*)d_in[5];
    } else {
        a0 = (const float*)d_in[0]; a1 = (const float*)d_in[1];
        a2 = (const float*)d_in[2]; h0 = (const float*)d_in[3];
        h1 = (const float*)d_in[4]; h2 = (const float*)d_in[5];
    }
    const float* w0 = (const float*)d_in[6];
    const float* w1 = (const float*)d_in[7];
    const float* w2 = (const float*)d_in[8];
    float* out = (float*)d_out;

    int E = in_sizes[0];
    int nq = E / 4, rem = E % 4;
    if (nq > 0) {
        int blocks = (nq + 255) / 256;
        gnn_quad<<<blocks, 256, 0, stream>>>(a0, a1, a2, h0, h1, h2, w0, w1, w2, out, nq);
    }
    if (rem > 0) {
        gnn_tail<<<1, 64, 0, stream>>>(a0, a1, a2, h0, h1, h2, w0, w1, w2, out, E, nq * 4);
    }
}

// Round 2
// 38.243 us; speedup vs baseline: 1.6566x; 1.6566x over previous
//
#include <hip/hip_runtime.h>
#include <utility>

// ============================================================================
// Compile-time Clebsch-Gordan coefficients (port of the e3nn-convention math
// from the reference). All evaluated by the compiler; zeros fold away.
// ============================================================================
namespace cgc {

constexpr double cfact(int n) {
    double r = 1.0;
    for (int i = 2; i <= n; ++i) r *= (double)i;
    return r;
}

constexpr double csqrt(double x) {
    if (x <= 0.0) return 0.0;
    double g = x > 1.0 ? x : 1.0;
    for (int it = 0; it < 64; ++it) {
        double ng = 0.5 * (g + x / g);
        if (ng == g) break;
        g = ng;
    }
    return g;
}

struct cplx { double re; double im; };
constexpr cplx cadd(cplx a, cplx b) { return {a.re + b.re, a.im + b.im}; }
constexpr cplx cmul(cplx a, cplx b) {
    return {a.re * b.re - a.im * b.im, a.re * b.im + a.im * b.re};
}
constexpr cplx cconj(cplx a) { return {a.re, -a.im}; }

constexpr double su2_cg_coef(int j1, int m1, int j2, int m2, int j3, int m3) {
    double pref = csqrt((2.0 * j3 + 1.0) * cfact(j3 + j1 - j2) * cfact(j3 - j1 + j2) *
                        cfact(j1 + j2 - j3) / cfact(j1 + j2 + j3 + 1));
    pref *= csqrt(cfact(j3 + m3) * cfact(j3 - m3) * cfact(j1 - m1) * cfact(j1 + m1) *
                  cfact(j2 - m2) * cfact(j2 + m2));
    double s = 0.0;
    for (int k = 0; k <= j1 + j2 - j3; ++k) {
        int d0 = k, d1 = j1 + j2 - j3 - k, d2 = j1 - m1 - k;
        int d3 = j2 + m2 - k, d4 = j3 - j2 + m1 + k, d5 = j3 - j1 - m2 + k;
        if (d0 < 0 || d1 < 0 || d2 < 0 || d3 < 0 || d4 < 0 || d5 < 0) continue;
        double denom = cfact(d0) * cfact(d1) * cfact(d2) * cfact(d3) * cfact(d4) * cfact(d5);
        s += ((k & 1) ? -1.0 : 1.0) / denom;
    }
    return pref * s;
}

struct T3  { double v[5][5][5]; };
struct M2  { cplx v[5][5]; };
struct CT3 { cplx v[5][5][5]; };

constexpr T3 su2_cg(int j1, int j2, int j3) {
    T3 C{};
    for (int m1 = -j1; m1 <= j1; ++m1)
        for (int m2 = -j2; m2 <= j2; ++m2) {
            int m3 = m1 + m2;
            if (m3 >= -j3 && m3 <= j3)
                C.v[j1 + m1][j2 + m2][j3 + m3] = su2_cg_coef(j1, m1, j2, m2, j3, m3);
        }
    return C;
}

constexpr M2 real_to_complex(int l) {
    M2 q{};
    const double s = csqrt(0.5);
    for (int m = -l; m < 0; ++m) {
        q.v[l + m][l - m] = cplx{s, 0.0};
        q.v[l + m][l + m] = cplx{0.0, -s};
    }
    q.v[l][l] = cplx{1.0, 0.0};
    for (int m = 1; m <= l; ++m) {
        double sg = (m & 1) ? -1.0 : 1.0;
        q.v[l + m][l + m] = cplx{sg * s, 0.0};
        q.v[l + m][l - m] = cplx{0.0, sg * s};
    }
    cplx ph{1.0, 0.0};
    for (int i = 0; i < l; ++i) ph = cmul(ph, cplx{0.0, -1.0});  // (-1j)^l
    for (int r = 0; r < 2 * l + 1; ++r)
        for (int c = 0; c < 2 * l + 1; ++c)
            q.v[r][c] = cmul(q.v[r][c], ph);
    return q;
}

constexpr T3 so3_cg(int l1, int l2, int l3) {
    M2 Q1 = real_to_complex(l1);
    M2 Q2 = real_to_complex(l2);
    M2 Q3 = real_to_complex(l3);
    T3 Cs = su2_cg(l1, l2, l3);
    int n1 = 2 * l1 + 1, n2 = 2 * l2 + 1, n3 = 2 * l3 + 1;
    CT3 t1{};
    for (int j = 0; j < n1; ++j)
        for (int k = 0; k < n2; ++k)
            for (int n = 0; n < n3; ++n) {
                cplx acc{0.0, 0.0};
                for (int i = 0; i < n1; ++i)
                    acc = cadd(acc, cmul(Q1.v[i][j], cplx{Cs.v[i][k][n], 0.0}));
                t1.v[j][k][n] = acc;
            }
    CT3 t2{};
    for (int j = 0; j < n1; ++j)
        for (int L = 0; L < n2; ++L)
            for (int n = 0; n < n3; ++n) {
                cplx acc{0.0, 0.0};
                for (int k = 0; k < n2; ++k)
                    acc = cadd(acc, cmul(Q2.v[k][L], t1.v[j][k][n]));
                t2.v[j][L][n] = acc;
            }
    T3 R{};
    double norm2 = 0.0;
    for (int j = 0; j < n1; ++j)
        for (int L = 0; L < n2; ++L)
            for (int m = 0; m < n3; ++m) {
                cplx acc{0.0, 0.0};
                for (int n = 0; n < n3; ++n)
                    acc = cadd(acc, cmul(cconj(Q3.v[n][m]), t2.v[j][L][n]));
                R.v[j][L][m] = acc.re;
                norm2 += acc.re * acc.re;
            }
    double nrm = csqrt(norm2);
    if (nrm > 0.0)
        for (int j = 0; j < n1; ++j)
            for (int L = 0; L < n2; ++L)
                for (int m = 0; m < n3; ++m)
                    R.v[j][L][m] /= nrm;
    return R;
}

template <int LA, int LH, int LO>
constexpr T3 CGT = so3_cg(LA, LH, LO);

}  // namespace cgc

// ============================================================================
// Device side
// ============================================================================
template <typename F, int... Is>
__device__ __forceinline__ void unroll_impl(F&& f, std::integer_sequence<int, Is...>) {
    (f(std::integral_constant<int, Is>{}), ...);
}
template <int N, typename F>
__device__ __forceinline__ void unroll(F&& f) {
    unroll_impl(static_cast<F&&>(f), std::make_integer_sequence<int, N>{});
}

// o[k] += w * sum_{i,j} C[i][j][k] * a[i] * h[j], zeros folded at compile time.
template <int LA, int LH, int LO>
__device__ __forceinline__ void combo(float w, const float* a, const float* h, float* o) {
    constexpr int DA = 2 * LA + 1, DH = 2 * LH + 1, DO = 2 * LO + 1;
    unroll<DO>([&](auto kc) {
        constexpr int k = decltype(kc)::value;
        float s = 0.f;
        unroll<DA * DH>([&](auto tc) {
            constexpr int t = decltype(tc)::value;
            constexpr int i = t / DH;
            constexpr int j = t % DH;
            constexpr double cd = cgc::CGT<LA, LH, LO>.v[i][j][k];
            if constexpr (cd > 1e-12 || cd < -1e-12) {
                constexpr float c = (float)cd;
                s = fmaf(c, a[i] * h[j], s);
            }
        });
        o[k] = fmaf(w, s, o[k]);
    });
}

__device__ __forceinline__ void compute_edge(const float* a, const float* h,
                                             const float* W0, const float* W1,
                                             const float* W2, float* o) {
#pragma unroll
    for (int k = 0; k < 9; ++k) o[k] = 0.f;
    // combo order == Python _valid_combos order (ai outer, hi inner)
    combo<0, 0, 0>(W0[0], a + 0, h + 0, o + 0);
    combo<1, 1, 0>(W0[1], a + 1, h + 1, o + 0);
    combo<2, 2, 0>(W0[2], a + 4, h + 4, o + 0);
    combo<0, 1, 1>(W1[0], a + 0, h + 1, o + 1);
    combo<1, 0, 1>(W1[1], a + 1, h + 0, o + 1);
    combo<1, 1, 1>(W1[2], a + 1, h + 1, o + 1);
    combo<1, 2, 1>(W1[3], a + 1, h + 4, o + 1);
    combo<2, 1, 1>(W1[4], a + 4, h + 1, o + 1);
    combo<2, 2, 1>(W1[5], a + 4, h + 4, o + 1);
    combo<0, 2, 2>(W2[0], a + 0, h + 4, o + 4);
    combo<1, 1, 2>(W2[1], a + 1, h + 1, o + 4);
    combo<1, 2, 2>(W2[2], a + 1, h + 4, o + 4);
    combo<2, 0, 2>(W2[3], a + 4, h + 0, o + 4);
    combo<2, 1, 2>(W2[4], a + 4, h + 1, o + 4);
    combo<2, 2, 2>(W2[5], a + 4, h + 4, o + 4);
}

// One edge per thread: every wave-level access is a dense, fully-coalesced
// contiguous region (stride 4/12/20/36 B across lanes — all lines fully used).
__global__ __launch_bounds__(256) void gnn_edge(
    const float* __restrict__ a0, const float* __restrict__ a1, const float* __restrict__ a2,
    const float* __restrict__ h0, const float* __restrict__ h1, const float* __restrict__ h2,
    const float* __restrict__ w0, const float* __restrict__ w1, const float* __restrict__ w2,
    float* __restrict__ out, int E) {
    int e = blockIdx.x * blockDim.x + threadIdx.x;
    if (e >= E) return;

    // wave-uniform weight loads -> scalarized by compiler
    float W0[3], W1[6], W2[6];
#pragma unroll
    for (int i = 0; i < 3; ++i) W0[i] = w0[i];
#pragma unroll
    for (int i = 0; i < 6; ++i) W1[i] = w1[i];
#pragma unroll
    for (int i = 0; i < 6; ++i) W2[i] = w2[i];

    size_t es = (size_t)e;
    float a[9], h[9], o[9];
    a[0] = a0[es];
    {
        const float* p = a1 + 3 * es;
#pragma unroll
        for (int c = 0; c < 3; ++c) a[1 + c] = p[c];
    }
    {
        const float* p = a2 + 5 * es;
#pragma unroll
        for (int c = 0; c < 5; ++c) a[4 + c] = p[c];
    }
    h[0] = h0[es];
    {
        const float* p = h1 + 3 * es;
#pragma unroll
        for (int c = 0; c < 3; ++c) h[1 + c] = p[c];
    }
    {
        const float* p = h2 + 5 * es;
#pragma unroll
        for (int c = 0; c < 5; ++c) h[4 + c] = p[c];
    }

    compute_edge(a, h, W0, W1, W2, o);

    float* po = out + 9 * es;
#pragma unroll
    for (int k = 0; k < 9; ++k) po[k] = o[k];
}

extern "C" void kernel_launch(void* const* d_in, const int* in_sizes, int n_in,
                              void* d_out, int out_size, void* d_ws, size_t ws_size,
                              hipStream_t stream) {
    (void)n_in; (void)d_ws; (void)ws_size; (void)out_size;
    const float *a0, *a1, *a2, *h0, *h1, *h2;
    // setup_inputs() dict order interleaves: a0,h0,a1,h1,a2,h2. Detect by sizes
    // in case the harness used the reference-signature order instead.
    if (in_sizes[1] == in_sizes[0]) {
        a0 = (const float*)d_in[0]; h0 = (const float*)d_in[1];
        a1 = (const float*)d_in[2]; h1 = (const float*)d_in[3];
        a2 = (const float*)d_in[4]; h2 = (const float*)d_in[5];
    } else {
        a0 = (const float*)d_in[0]; a1 = (const float*)d_in[1];
        a2 = (const float*)d_in[2]; h0 = (const float*)d_in[3];
        h1 = (const float*)d_in[4]; h2 = (const float*)d_in[5];
    }
    const float* w0 = (const float*)d_in[6];
    const float* w1 = (const float*)d_in[7];
    const float* w2 = (const float*)d_in[8];
    float* out = (float*)d_out;

    int E = in_sizes[0];
    int blocks = (E + 255) / 256;
    gnn_edge<<<blocks, 256, 0, stream>>>(a0, a1, a2, h0, h1, h2, w0, w1, w2, out, E);
}